// Round 16
// baseline (182.075 us; speedup 1.0000x reference)
//
#include <hip/hip_runtime.h>
#include <hip/hip_bf16.h>
#include <cstdint>

#define DEV __device__ __forceinline__

typedef __attribute__((ext_vector_type(4))) float f32x4;
typedef __attribute__((ext_vector_type(8))) short b16x8;
typedef __attribute__((ext_vector_type(4))) unsigned short u16x4;
typedef __attribute__((ext_vector_type(8))) unsigned short u16x8;
typedef __attribute__((ext_vector_type(2))) unsigned int u32x2;
typedef __attribute__((ext_vector_type(4))) unsigned int u32x4;

typedef __attribute__((address_space(1))) void gvoid_t;
typedef __attribute__((address_space(3))) void lvoid_t;

static constexpr int Bsz = 8, Ssz = 1024, Dsz = 1024;
static constexpr int Mrows = Bsz * Ssz;  // 8192

// async global->LDS, 16B per lane; lds base must be wave-uniform (HW adds lane*16)
DEV void gld16(const void* g, void* l) {
  __builtin_amdgcn_global_load_lds((gvoid_t*)(uintptr_t)g,
                                   (lvoid_t*)(unsigned)(uintptr_t)l, 16, 0, 0);
}

// fp32 -> bf16 RNE (finite inputs only) — cold paths only
DEV unsigned short f2bf(float x) {
  unsigned int u = __float_as_uint(x);
  u += 0x7fffu + ((u >> 16) & 1u);
  return (unsigned short)(u >> 16);
}

// hot path: paired convert -> v_cvt_pk_bf16_f32
DEV unsigned int cvt2(float lo, float hi) {
  __hip_bfloat162 h = __float22bfloat162_rn(make_float2(lo, hi));
  unsigned int u;
  __builtin_memcpy(&u, &h, 4);
  return u;
}

// raw v_exp_f32 (2^x). Safe here: x in [0, ~26] (post-ReLU scores).
// [R13 confirmed: attn 65.5 -> 55.3 us vs OCML exp2f]
DEV float fexp2(float x) {
#if __has_builtin(__builtin_amdgcn_exp2f)
  return __builtin_amdgcn_exp2f(x);
#else
  return exp2f(x);
#endif
}

// counted-waitcnt discipline (rule #18: sched_barrier after asm waits)
#define WAIT_LGKM0                                     \
  asm volatile("s_waitcnt lgkmcnt(0)" ::: "memory");   \
  __builtin_amdgcn_sched_barrier(0)
#define WAIT_VM(N)                                         \
  asm volatile("s_waitcnt vmcnt(" #N ")" ::: "memory");    \
  __builtin_amdgcn_sched_barrier(0)
#define RAW_BAR                       \
  __builtin_amdgcn_s_barrier();       \
  __builtin_amdgcn_sched_barrier(0)

// ---------------------------------------------------------------------------
// Kernel 1: convert+transpose 4 weight matrices: Wt[w][n][k] = bf16(W[k][n])
// ---------------------------------------------------------------------------
__global__ __launch_bounds__(256) void wconv_kernel(
    const float* __restrict__ WQ, const float* __restrict__ WK,
    const float* __restrict__ WV, const float* __restrict__ WO,
    unsigned short* __restrict__ Wt) {
  __shared__ float tile[64][65];
  const int w = blockIdx.z;
  const float* W = (w == 0) ? WQ : (w == 1) ? WK : (w == 2) ? WV : WO;
  const int k0 = blockIdx.x * 64, n0 = blockIdx.y * 64;
  const int t = threadIdx.x;
  {
    const int r = t >> 4;
    const int c = (t & 15) * 4;
#pragma unroll
    for (int i = 0; i < 4; ++i) {
      f32x4 v = *(const f32x4*)(W + (size_t)(k0 + i * 16 + r) * Dsz + n0 + c);
      tile[i * 16 + r][c + 0] = v[0];
      tile[i * 16 + r][c + 1] = v[1];
      tile[i * 16 + r][c + 2] = v[2];
      tile[i * 16 + r][c + 3] = v[3];
    }
  }
  __syncthreads();
  {
    const int n = t >> 2;
    const int ks = (t & 3) * 16;
    unsigned short* dst =
        Wt + (size_t)w * Dsz * Dsz + (size_t)(n0 + n) * Dsz + k0 + ks;
#pragma unroll
    for (int j = 0; j < 16; j += 4) {
      u16x4 p;
#pragma unroll
      for (int jj = 0; jj < 4; ++jj) p[jj] = f2bf(tile[ks + j + jj][n]);
      *(u16x4*)(dst + j) = p;
    }
  }
}

// ---------------------------------------------------------------------------
// Kernel 2a (proj3): 128(M)x256(N) GEMM, fp32 A, 8 waves — R16: raw-barrier
// counted-vmcnt pipeline (no vmcnt(0) drain at barriers).
//   A: 2-deep banked register prefetch (loadA(kt+2) -> consumed 2 barriers
//      later; ~1500cy coverage >= 900cy HBM latency).
//   B: LDS dbuf, gld16 1-ahead; B(kt) drained per-wave by counted vmcnt(4)
//      after writeA (outstanding there = B(kt)x4 old + A(kt+1)x4 new;
//      prologue ordered A0,B0,A1 to preserve the invariant; last iter
//      vmcnt(0) since no A remains).
//   Races: Asl RAW/WAR via lgkm(0)+barriers; Bsl RAW via vmcnt(4) before
//   barrier1; Bsl WAR via dbuf + lgkm-drained reads before barrier2.
// ---------------------------------------------------------------------------
template <int OUT_MODE>
DEV void gemm_body_f32(unsigned short* __restrict__ Asl,   // 16 KB
                       unsigned short* __restrict__ Bsl,   // 2 x 32 KB
                       const float* __restrict__ A,
                       const unsigned short* __restrict__ Bt,
                       const float* __restrict__ bias, void* __restrict__ C_,
                       int m0, int n0, float outscale) {
  constexpr int Kd = 1024, Nd = 1024;
  const int t = threadIdx.x, lane = t & 63, wave = t >> 6;
  const int grp = lane >> 4, r16 = lane & 15;
  const int wm = wave >> 2, wn = wave & 3;  // 2m x 4n waves, 64x64 each
  const int swz = (r16 & 7) << 4;
  f32x4 acc[4][4] = {};
  f32x4 areg[2][2][2];  // [bank][chunk][half]: 2-deep A prefetch, 32 VGPR

  auto loadA = [&](int kt, int bank) {
#pragma unroll
    for (int it = 0; it < 2; ++it) {
      int chunk = it * 512 + t;
      int row = chunk >> 3, c = chunk & 7;
      int csw = c ^ (row & 7);
      const float* src = A + (size_t)(m0 + row) * Kd + kt + csw * 8;
      areg[bank][it][0] = *(const f32x4*)src;
      areg[bank][it][1] = *(const f32x4*)(src + 4);
    }
  };
  auto writeA = [&](int bank) {
#pragma unroll
    for (int it = 0; it < 2; ++it) {
      int chunk = it * 512 + t;
      u32x4 w;
      w[0] = cvt2(areg[bank][it][0][0], areg[bank][it][0][1]);
      w[1] = cvt2(areg[bank][it][0][2], areg[bank][it][0][3]);
      w[2] = cvt2(areg[bank][it][1][0], areg[bank][it][1][1]);
      w[3] = cvt2(areg[bank][it][1][2], areg[bank][it][1][3]);
      *(u32x4*)((char*)Asl + chunk * 16) = w;
    }
  };
  auto stageB = [&](int kt, int pb) {
#pragma unroll
    for (int j = 0; j < 4; ++j) {
      int chunk = (wave * 4 + j) * 64 + lane;  // 0..2047 -> 256 rows
      int row = chunk >> 3, c = chunk & 7;
      int csw = c ^ (row & 7);
      gld16(Bt + (size_t)(n0 + row) * Kd + kt + csw * 8,
            (char*)Bsl + pb * 32768 + (wave * 4 + j) * 1024);
    }
  };

  // prologue: A0, B0, A1 (this order keeps the vmcnt invariant)
  loadA(0, 0);
  __builtin_amdgcn_sched_barrier(0);
  stageB(0, 0);
  __builtin_amdgcn_sched_barrier(0);
  loadA(64, 1);
  __builtin_amdgcn_sched_barrier(0);

  int cur = 0;
  for (int kt = 0; kt < Kd; kt += 64) {
    const int bank = (kt >> 6) & 1;
    writeA(bank);  // compiler waits A(kt) regs (in-order: drains all older vm)
    if (kt == Kd - 64) {
      WAIT_VM(0);  // tail: only B(kt) outstanding -> full drain
    } else {
      WAIT_VM(4);  // drain B(kt) (older 4); leave A(kt+1) (newer 4) in flight
    }
    WAIT_LGKM0;   // A ds_writes visible
    RAW_BAR;      // barrier1: Asl + Bsl[cur] ready for all waves
    if (kt < Kd - 64) {
      stageB(kt + 64, cur ^ 1);  // 4 vm; lands by next iter's vmcnt(4)
      __builtin_amdgcn_sched_barrier(0);
      if (kt < Kd - 128) loadA(kt + 128, bank);  // 4 vm, 2-deep
      __builtin_amdgcn_sched_barrier(0);
    }
#pragma unroll
    for (int cs = 0; cs < 2; ++cs) {
      b16x8 af[4], bfr[4];
#pragma unroll
      for (int mi = 0; mi < 4; ++mi)
        af[mi] = *(const b16x8*)((char*)Asl + (wm * 64 + mi * 16 + r16) * 128 +
                                 ((cs * 64 + grp * 16) ^ swz));
#pragma unroll
      for (int ni = 0; ni < 4; ++ni)
        bfr[ni] = *(const b16x8*)((char*)Bsl + cur * 32768 +
                                  (wn * 64 + ni * 16 + r16) * 128 +
                                  ((cs * 64 + grp * 16) ^ swz));
#pragma unroll
      for (int mi = 0; mi < 4; ++mi)
#pragma unroll
        for (int ni = 0; ni < 4; ++ni)
          acc[mi][ni] = __builtin_amdgcn_mfma_f32_16x16x32_bf16(
              af[mi], bfr[ni], acc[mi][ni], 0, 0, 0);
    }
    WAIT_LGKM0;  // own frag reads complete
    RAW_BAR;     // barrier2: Asl safe to overwrite next iter (NO vm drain)
    cur ^= 1;
  }
  // epilogue: bias + relu (+scale); C/D layout: col=lane&15, row=(lane>>4)*4+r
#pragma unroll
  for (int mi = 0; mi < 4; ++mi) {
#pragma unroll
    for (int ni = 0; ni < 4; ++ni) {
      int col = n0 + wn * 64 + ni * 16 + r16;
      float bv = bias[col];
      int row0 = m0 + wm * 64 + mi * 16 + grp * 4;
      if constexpr (OUT_MODE == 2) {
        int bb = row0 >> 10, s = row0 & 1023;
        u16x4 pk;
#pragma unroll
        for (int r = 0; r < 4; ++r)
          pk[r] = f2bf(fmaxf(acc[mi][ni][r] + bv, 0.0f) * outscale);
        *(u16x4*)((unsigned short*)C_ +
                  (((size_t)(bb * 1024 + col)) << 10) + s) = pk;
      } else {
#pragma unroll
        for (int r = 0; r < 4; ++r) {
          float v = fmaxf(acc[mi][ni][r] + bv, 0.0f) * outscale;
          ((unsigned short*)C_)[(size_t)(row0 + r) * Nd + col] = f2bf(v);
        }
      }
    }
  }
}

// ---------------------------------------------------------------------------
// Kernel 2b (out_gemm): 2-barrier body, both operands bf16 gld16. (Unchanged.)
// ---------------------------------------------------------------------------
DEV void gemm_body_bf16(unsigned short* __restrict__ Asl,
                        unsigned short* __restrict__ Bsl,
                        const unsigned short* __restrict__ A,
                        const unsigned short* __restrict__ Bt,
                        const float* __restrict__ bias, float* __restrict__ C_,
                        int m0, int n0) {
  constexpr int Kd = 1024, Nd = 1024;
  const int t = threadIdx.x, lane = t & 63, wave = t >> 6;
  const int grp = lane >> 4, r16 = lane & 15;
  const int wm = wave >> 1, wn = wave & 1;
  const int swz = (r16 & 7) << 4;
  f32x4 acc[4][4] = {};
  for (int kt = 0; kt < Kd; kt += 64) {
#pragma unroll
    for (int j = 0; j < 4; ++j) {
      int chunk = (wave * 4 + j) * 64 + lane;
      int row = chunk >> 3, c = chunk & 7;
      int csw = c ^ (row & 7);
      gld16(Bt + (size_t)(n0 + row) * Kd + kt + csw * 8,
            (char*)Bsl + (wave * 4 + j) * 1024);
      gld16(A + (size_t)(m0 + row) * Kd + kt + csw * 8,
            (char*)Asl + (wave * 4 + j) * 1024);
    }
    __syncthreads();
#pragma unroll
    for (int cs = 0; cs < 2; ++cs) {
      b16x8 af[4], bfr[4];
#pragma unroll
      for (int mi = 0; mi < 4; ++mi)
        af[mi] = *(const b16x8*)((char*)Asl + (wm * 64 + mi * 16 + r16) * 128 +
                                 ((cs * 64 + grp * 16) ^ swz));
#pragma unroll
      for (int ni = 0; ni < 4; ++ni)
        bfr[ni] = *(const b16x8*)((char*)Bsl + (wn * 64 + ni * 16 + r16) * 128 +
                                  ((cs * 64 + grp * 16) ^ swz));
#pragma unroll
      for (int mi = 0; mi < 4; ++mi)
#pragma unroll
        for (int ni = 0; ni < 4; ++ni)
          acc[mi][ni] = __builtin_amdgcn_mfma_f32_16x16x32_bf16(
              af[mi], bfr[ni], acc[mi][ni], 0, 0, 0);
    }
    __syncthreads();
  }
#pragma unroll
  for (int mi = 0; mi < 4; ++mi) {
#pragma unroll
    for (int ni = 0; ni < 4; ++ni) {
      int col = n0 + wn * 64 + ni * 16 + r16;
      float bv = bias[col];
      int row0 = m0 + wm * 64 + mi * 16 + grp * 4;
#pragma unroll
      for (int r = 0; r < 4; ++r) {
        float v = fmaxf(acc[mi][ni][r] + bv, 0.0f);
        C_[(size_t)(row0 + r) * Nd + col] = v;
      }
    }
  }
}

// Q projection pre-scaled by 1/sqrt(D)*log2(e) so attention softmax runs in
// exp2 domain with no per-score scaling (relu commutes with positive scale).
static constexpr float QSCALE = 0.03125f * 1.4426950408889634f;

// x-grid 256 = 8 xcd * 32; per XCD: 8 m-panels x 4 n-tiles per z ->
// A-panel shared by 4 blocks in-XCD, weight (2MB) L2-resident.
__global__ __launch_bounds__(512) void proj3_kernel(
    const float* __restrict__ Q, const float* __restrict__ K,
    const float* __restrict__ V, const unsigned short* __restrict__ Wt,
    const float* __restrict__ bQ, const float* __restrict__ bK,
    const float* __restrict__ bV, unsigned short* __restrict__ Qp,
    unsigned short* __restrict__ Kp, unsigned short* __restrict__ VpT) {
  __shared__ unsigned short Asl[128 * 64] __attribute__((aligned(16)));
  __shared__ unsigned short Bsl[2 * 256 * 64] __attribute__((aligned(16)));
  const size_t DD = (size_t)Dsz * Dsz;
  const int bid = blockIdx.x;  // 256 = 8 xcd * 32
  const int id2 = (bid & 7) * 32 + (bid >> 3);
  const int n0 = (id2 & 3) * 256, m0 = (id2 >> 2) * 128;
  const int z = blockIdx.z;
  if (z == 0)
    gemm_body_f32<1>(Asl, Bsl, Q, Wt, bQ, Qp, m0, n0, QSCALE);
  else if (z == 1)
    gemm_body_f32<1>(Asl, Bsl, K, Wt + DD, bK, Kp, m0, n0, 1.0f);
  else
    gemm_body_f32<2>(Asl, Bsl, V, Wt + 2 * DD, bV, VpT, m0, n0, 1.0f);
}

__global__ __launch_bounds__(256) void out_gemm_kernel(
    const unsigned short* __restrict__ AO,
    const unsigned short* __restrict__ WOt, const float* __restrict__ bO,
    float* __restrict__ Out) {
  __shared__ unsigned short Asl[128 * 64] __attribute__((aligned(16)));
  __shared__ unsigned short Bsl[128 * 64] __attribute__((aligned(16)));
  const int bid = blockIdx.x;
  const int id2 = (bid & 7) * 64 + (bid >> 3);
  const int n0 = (id2 & 7) * 128, m0 = (id2 >> 3) * 128;
  gemm_body_bf16(Asl, Bsl, AO, WOt, bO, Out, m0, n0);
}

// ---------------------------------------------------------------------------
// Kernel 4: flash attention — R13's proven 2-subtile version, verbatim
// (55.3 us measured). Swapped-QK^T, NO max tracking, fexp2, l via
// ones-column, setprio, issue-early dbuf staging.
// ---------------------------------------------------------------------------
__global__ __launch_bounds__(512, 4) void attn_kernel(
    const unsigned short* __restrict__ Qp, const unsigned short* __restrict__ Kp,
    const unsigned short* __restrict__ VpT, unsigned short* __restrict__ AO) {
  __shared__ unsigned short Ks[2][64 * 64] __attribute__((aligned(16)));
  __shared__ unsigned short Vs[2][64 * 64] __attribute__((aligned(16)));
  __shared__ unsigned short Ps[16][16 * 64] __attribute__((aligned(16)));
  const int t = threadIdx.x, lane = t & 63, wave = t >> 6;
  const int grp = lane >> 4, r16 = lane & 15;
  const int bid = blockIdx.x;
  const int id2 = (bid & 7) * 64 + (bid >> 3);
  const int q0 = (id2 & 3) * 256;
  const int bh = id2 >> 2;
  const int b = bh & 7, head = bh >> 3;

  // staging: 512 threads cover K tile (512 x 16B) and V tile each 1:1
  const int srow = t >> 3, scc = t & 7;
  const int csw = scc ^ (srow & 7);
  const unsigned short* kbase = Kp + ((size_t)b * Ssz) * Dsz + head * 64;
  const unsigned short* vbase = VpT + ((size_t)b * Dsz + head * 64) * Ssz;

  // Q fragments for both subtiles (B-operand layout: row=lane&15, k=8*grp+j)
  const int sqA = q0 + wave * 16 + r16;
  const unsigned short* qbA = Qp + ((size_t)b * Ssz + sqA) * Dsz + head * 64;
  const unsigned short* qbB = qbA + (size_t)128 * Dsz;
  b16x8 qfA0 = *(const b16x8*)(qbA + grp * 8);
  b16x8 qfA1 = *(const b16x8*)(qbA + 32 + grp * 8);
  b16x8 qfB0 = *(const b16x8*)(qbB + grp * 8);
  b16x8 qfB1 = *(const b16x8*)(qbB + 32 + grp * 8);

  f32x4 oA[4] = {}, oB[4] = {};
  f32x4 olA = {}, olB = {};
  const f32x4 zero4 = {0.0f, 0.0f, 0.0f, 0.0f};
  const b16x8 ones = {16256, 16256, 16256, 16256,
                      16256, 16256, 16256, 16256};  // bf16 1.0 x8

  auto stage = [&](int kv0, int pb) {
    gld16(kbase + (size_t)(kv0 + srow) * Dsz + csw * 8,
          (char*)Ks[pb] + wave * 1024);
    gld16(vbase + (size_t)srow * Ssz + kv0 + csw * 8,
          (char*)Vs[pb] + wave * 1024);
  };

  stage(0, 0);
  __syncthreads();
  int cur = 0;

  for (int it = 0; it < 16; ++it) {
    if (it < 15) stage((it + 1) * 64, cur ^ 1);  // issue-early: overlaps compute

    // S^T = K Q^T for both subtiles, sharing the K fragment loads.
    __builtin_amdgcn_s_setprio(1);
    f32x4 scA[4], scB[4];
#pragma unroll
    for (int f = 0; f < 4; ++f) {
      int k = f * 16 + r16;
      int kswz = (k & 7) << 4;
      const char* kb = (const char*)Ks[cur] + k * 128;
      b16x8 kf0 = *(const b16x8*)(kb + ((grp * 16) ^ kswz));
      b16x8 kf1 = *(const b16x8*)(kb + ((64 + grp * 16) ^ kswz));
      f32x4 sA = __builtin_amdgcn_mfma_f32_16x16x32_bf16(kf0, qfA0, zero4, 0, 0, 0);
      scA[f] = __builtin_amdgcn_mfma_f32_16x16x32_bf16(kf1, qfA1, sA, 0, 0, 0);
      f32x4 sB = __builtin_amdgcn_mfma_f32_16x16x32_bf16(kf0, qfB0, zero4, 0, 0, 0);
      scB[f] = __builtin_amdgcn_mfma_f32_16x16x32_bf16(kf1, qfB1, sB, 0, 0, 0);
    }
    __builtin_amdgcn_s_setprio(0);

    // p = exp2(s) via raw v_exp_f32; pack P rows: 8B writes via cvt_pk
    {
      int qs = (r16 & 7) << 4;
      char* prowA = (char*)Ps + (wave * 2 + 0) * 2048 + r16 * 128;
      char* prowB = (char*)Ps + (wave * 2 + 1) * 2048 + r16 * 128;
#pragma unroll
      for (int f = 0; f < 4; ++f) {
        u32x2 w;
        w[0] = cvt2(fexp2(scA[f][0]), fexp2(scA[f][1]));
        w[1] = cvt2(fexp2(scA[f][2]), fexp2(scA[f][3]));
        *(u32x2*)(prowA + ((f * 32 + grp * 8) ^ qs)) = w;
      }
#pragma unroll
      for (int f = 0; f < 4; ++f) {
        u32x2 w;
        w[0] = cvt2(fexp2(scB[f][0]), fexp2(scB[f][1]));
        w[1] = cvt2(fexp2(scB[f][2]), fexp2(scB[f][3]));
        *(u32x2*)(prowB + ((f * 32 + grp * 8) ^ qs)) = w;
      }
    }

    // O += P V ; l += P 1 — V fragments shared across subtiles
    __builtin_amdgcn_s_setprio(1);
#pragma unroll
    for (int ks = 0; ks < 2; ++ks) {
      int pswz = (r16 & 7) << 4;
      int poff = r16 * 128 + ((ks * 64 + grp * 16) ^ pswz);
      b16x8 paA = *(const b16x8*)((char*)Ps + (wave * 2 + 0) * 2048 + poff);
      b16x8 paB = *(const b16x8*)((char*)Ps + (wave * 2 + 1) * 2048 + poff);
      olA = __builtin_amdgcn_mfma_f32_16x16x32_bf16(paA, ones, olA, 0, 0, 0);
      olB = __builtin_amdgcn_mfma_f32_16x16x32_bf16(paB, ones, olB, 0, 0, 0);
#pragma unroll
      for (int fc = 0; fc < 4; ++fc) {
        int d = fc * 16 + r16;
        int vswz = (d & 7) << 4;
        b16x8 vb = *(const b16x8*)((char*)Vs[cur] + d * 128 +
                                   ((ks * 64 + grp * 16) ^ vswz));
        oA[fc] = __builtin_amdgcn_mfma_f32_16x16x32_bf16(paA, vb, oA[fc], 0, 0, 0);
        oB[fc] = __builtin_amdgcn_mfma_f32_16x16x32_bf16(paB, vb, oB[fc], 0, 0, 0);
      }
    }
    __builtin_amdgcn_s_setprio(0);
    __syncthreads();  // drains next-tile vmcnt after compute; read-fence for swap
    cur ^= 1;
  }

  // O /= l ; o and ol share the D-layout (row q = grp*4+r) -> no broadcast
#pragma unroll
  for (int fc = 0; fc < 4; ++fc) {
    int col = head * 64 + fc * 16 + r16;
#pragma unroll
    for (int r = 0; r < 4; ++r) {
      int rowA = q0 + wave * 16 + grp * 4 + r;
      AO[((size_t)b * Ssz + rowA) * Dsz + col] = f2bf(oA[fc][r] / olA[r]);
      AO[((size_t)b * Ssz + rowA + 128) * Dsz + col] = f2bf(oB[fc][r] / olB[r]);
    }
  }
}

// ---------------------------------------------------------------------------
extern "C" void kernel_launch(void* const* d_in, const int* in_sizes, int n_in,
                              void* d_out, int out_size, void* d_ws,
                              size_t ws_size, hipStream_t stream) {
  const float* Q = (const float*)d_in[0];
  const float* K = (const float*)d_in[1];
  const float* V = (const float*)d_in[2];
  const float* WQ = (const float*)d_in[3];
  const float* bQ = (const float*)d_in[4];
  const float* WK = (const float*)d_in[5];
  const float* bK = (const float*)d_in[6];
  const float* WV = (const float*)d_in[7];
  const float* bV = (const float*)d_in[8];
  const float* WO = (const float*)d_in[9];
  const float* bO = (const float*)d_in[10];

  char* ws = (char*)d_ws;
  const size_t MB = 1024ull * 1024ull;
  const size_t DD = (size_t)Dsz * Dsz;
  unsigned short* Wt = (unsigned short*)(ws);             // 8 MB: 4x[n][k] bf16
  unsigned short* Qp = (unsigned short*)(ws + 8 * MB);    // 16 MB
  unsigned short* Kp = (unsigned short*)(ws + 24 * MB);   // 16 MB
  unsigned short* VpT = (unsigned short*)(ws + 40 * MB);  // 16 MB
  unsigned short* AO = (unsigned short*)(ws + 56 * MB);   // 16 MB

  wconv_kernel<<<dim3(16, 16, 4), 256, 0, stream>>>(WQ, WK, WV, WO, Wt);
  proj3_kernel<<<dim3(256, 1, 3), 512, 0, stream>>>(Q, K, V, Wt, bQ, bK, bV,
                                                    Qp, Kp, VpT);
  attn_kernel<<<512, 512, 0, stream>>>(Qp, Kp, VpT, AO);
  out_gemm_kernel<<<512, 256, 0, stream>>>(AO, Wt + 3 * DD, bO, (float*)d_out);
}

// Round 17
// 152.551 us; speedup vs baseline: 1.1935x; 1.1935x over previous
//
#include <hip/hip_runtime.h>
#include <hip/hip_bf16.h>
#include <cstdint>

#define DEV __device__ __forceinline__

typedef __attribute__((ext_vector_type(4))) float f32x4;
typedef __attribute__((ext_vector_type(8))) short b16x8;
typedef __attribute__((ext_vector_type(4))) unsigned short u16x4;
typedef __attribute__((ext_vector_type(8))) unsigned short u16x8;
typedef __attribute__((ext_vector_type(2))) unsigned int u32x2;
typedef __attribute__((ext_vector_type(4))) unsigned int u32x4;

typedef __attribute__((address_space(1))) void gvoid_t;
typedef __attribute__((address_space(3))) void lvoid_t;

static constexpr int Bsz = 8, Ssz = 1024, Dsz = 1024;
static constexpr int Mrows = Bsz * Ssz;  // 8192

// async global->LDS, 16B per lane; lds base must be wave-uniform (HW adds lane*16)
DEV void gld16(const void* g, void* l) {
  __builtin_amdgcn_global_load_lds((gvoid_t*)(uintptr_t)g,
                                   (lvoid_t*)(unsigned)(uintptr_t)l, 16, 0, 0);
}

// fp32 -> bf16 RNE (finite inputs only) — cold paths only
DEV unsigned short f2bf(float x) {
  unsigned int u = __float_as_uint(x);
  u += 0x7fffu + ((u >> 16) & 1u);
  return (unsigned short)(u >> 16);
}

// hot path: paired convert -> v_cvt_pk_bf16_f32
DEV unsigned int cvt2(float lo, float hi) {
  __hip_bfloat162 h = __float22bfloat162_rn(make_float2(lo, hi));
  unsigned int u;
  __builtin_memcpy(&u, &h, 4);
  return u;
}

// raw v_exp_f32 (2^x). Safe here: x in [0, ~26] (post-ReLU scores).
// [R13 confirmed: attn 65.5 -> 55.3 us vs OCML exp2f]
DEV float fexp2(float x) {
#if __has_builtin(__builtin_amdgcn_exp2f)
  return __builtin_amdgcn_exp2f(x);
#else
  return exp2f(x);
#endif
}

// ---------------------------------------------------------------------------
// Kernel 1: convert+transpose 4 weight matrices: Wt[w][n][k] = bf16(W[k][n])
// ---------------------------------------------------------------------------
__global__ __launch_bounds__(256) void wconv_kernel(
    const float* __restrict__ WQ, const float* __restrict__ WK,
    const float* __restrict__ WV, const float* __restrict__ WO,
    unsigned short* __restrict__ Wt) {
  __shared__ float tile[64][65];
  const int w = blockIdx.z;
  const float* W = (w == 0) ? WQ : (w == 1) ? WK : (w == 2) ? WV : WO;
  const int k0 = blockIdx.x * 64, n0 = blockIdx.y * 64;
  const int t = threadIdx.x;
  {
    const int r = t >> 4;
    const int c = (t & 15) * 4;
#pragma unroll
    for (int i = 0; i < 4; ++i) {
      f32x4 v = *(const f32x4*)(W + (size_t)(k0 + i * 16 + r) * Dsz + n0 + c);
      tile[i * 16 + r][c + 0] = v[0];
      tile[i * 16 + r][c + 1] = v[1];
      tile[i * 16 + r][c + 2] = v[2];
      tile[i * 16 + r][c + 3] = v[3];
    }
  }
  __syncthreads();
  {
    const int n = t >> 2;
    const int ks = (t & 3) * 16;
    unsigned short* dst =
        Wt + (size_t)w * Dsz * Dsz + (size_t)(n0 + n) * Dsz + k0 + ks;
#pragma unroll
    for (int j = 0; j < 16; j += 4) {
      u16x4 p;
#pragma unroll
      for (int jj = 0; jj < 4; ++jj) p[jj] = f2bf(tile[ks + j + jj][n]);
      *(u16x4*)(dst + j) = p;
    }
  }
}

// ---------------------------------------------------------------------------
// Kernel 2a (proj3): pipelined 128(M)x256(N)-tile GEMM, fp32 A, 8 waves.
//   A: reg-prefetch 1 K-step ahead; B: LDS dbuf staged via gld16.
//   R17: barrier2 is lgkm-only (raw s_barrier, NO vmcnt drain) — its only
//   correctness role is the Asl WAR hazard (LDS reads done), which lgkm(0)
//   covers. stageB(kt+64)+loadA(kt+64) stay in flight across it and drain
//   at barrier1 (full __syncthreads) with writeA's convert-chain as extra
//   coverage. R16's failure was 6x sched_barrier(0)/iter order-pinning
//   (m141); this uses 2 pin-points total.
//   OUT_MODE: 1 = bf16 row-major, 2 = bf16 transposed VpT[b][col][s]
// ---------------------------------------------------------------------------
template <int OUT_MODE>
DEV void gemm_body_f32(unsigned short* __restrict__ Asl,   // 16 KB
                       unsigned short* __restrict__ Bsl,   // 2 x 32 KB
                       const float* __restrict__ A,
                       const unsigned short* __restrict__ Bt,
                       const float* __restrict__ bias, void* __restrict__ C_,
                       int m0, int n0, float outscale) {
  constexpr int Kd = 1024, Nd = 1024;
  const int t = threadIdx.x, lane = t & 63, wave = t >> 6;
  const int grp = lane >> 4, r16 = lane & 15;
  const int wm = wave >> 2, wn = wave & 3;  // 2m x 4n waves, 64x64 each
  const int swz = (r16 & 7) << 4;
  f32x4 acc[4][4] = {};
  f32x4 areg[2][2];  // A prefetch regs: 2 chunks x 8 floats = 16 VGPR

  auto loadA = [&](int kt) {
#pragma unroll
    for (int it = 0; it < 2; ++it) {
      int chunk = it * 512 + t;
      int row = chunk >> 3, c = chunk & 7;
      int csw = c ^ (row & 7);
      const float* src = A + (size_t)(m0 + row) * Kd + kt + csw * 8;
      areg[it][0] = *(const f32x4*)src;
      areg[it][1] = *(const f32x4*)(src + 4);
    }
  };
  auto writeA = [&]() {
#pragma unroll
    for (int it = 0; it < 2; ++it) {
      int chunk = it * 512 + t;
      u32x4 w;
      w[0] = cvt2(areg[it][0][0], areg[it][0][1]);
      w[1] = cvt2(areg[it][0][2], areg[it][0][3]);
      w[2] = cvt2(areg[it][1][0], areg[it][1][1]);
      w[3] = cvt2(areg[it][1][2], areg[it][1][3]);
      *(u32x4*)((char*)Asl + chunk * 16) = w;
    }
  };
  auto stageB = [&](int kt, int pb) {
#pragma unroll
    for (int j = 0; j < 4; ++j) {
      int chunk = (wave * 4 + j) * 64 + lane;  // 0..2047 -> 256 rows
      int row = chunk >> 3, c = chunk & 7;
      int csw = c ^ (row & 7);
      gld16(Bt + (size_t)(n0 + row) * Kd + kt + csw * 8,
            (char*)Bsl + pb * 32768 + (wave * 4 + j) * 1024);
    }
  };

  loadA(0);
  stageB(0, 0);  // prologue B[0]: drained at first barrier1 (one-time cost)
  int cur = 0;
  for (int kt = 0; kt < Kd; kt += 64) {
    writeA();        // cvt+write A[kt] (compiler waits its glb loads here)
    __syncthreads(); // barrier1: full drain — Asl visible, Bsl[cur] landed
    if (kt < Kd - 64) {
      stageB(kt + 64, cur ^ 1);  // stays in flight across barrier2
      loadA(kt + 64);            // A regs for next iter
    }
#pragma unroll
    for (int cs = 0; cs < 2; ++cs) {
      b16x8 af[4], bfr[4];
#pragma unroll
      for (int mi = 0; mi < 4; ++mi)
        af[mi] = *(const b16x8*)((char*)Asl + (wm * 64 + mi * 16 + r16) * 128 +
                                 ((cs * 64 + grp * 16) ^ swz));
#pragma unroll
      for (int ni = 0; ni < 4; ++ni)
        bfr[ni] = *(const b16x8*)((char*)Bsl + cur * 32768 +
                                  (wn * 64 + ni * 16 + r16) * 128 +
                                  ((cs * 64 + grp * 16) ^ swz));
#pragma unroll
      for (int mi = 0; mi < 4; ++mi)
#pragma unroll
        for (int ni = 0; ni < 4; ++ni)
          acc[mi][ni] = __builtin_amdgcn_mfma_f32_16x16x32_bf16(
              af[mi], bfr[ni], acc[mi][ni], 0, 0, 0);
    }
    // barrier2 (lgkm-only): guards Asl WAR; does NOT drain vmcnt
    asm volatile("s_waitcnt lgkmcnt(0)" ::: "memory");
    __builtin_amdgcn_s_barrier();
    __builtin_amdgcn_sched_barrier(0);
    cur ^= 1;
  }
  // epilogue: bias + relu (+scale); C/D layout: col=lane&15, row=(lane>>4)*4+r
#pragma unroll
  for (int mi = 0; mi < 4; ++mi) {
#pragma unroll
    for (int ni = 0; ni < 4; ++ni) {
      int col = n0 + wn * 64 + ni * 16 + r16;
      float bv = bias[col];
      int row0 = m0 + wm * 64 + mi * 16 + grp * 4;
      if constexpr (OUT_MODE == 2) {
        int bb = row0 >> 10, s = row0 & 1023;
        u16x4 pk;
#pragma unroll
        for (int r = 0; r < 4; ++r)
          pk[r] = f2bf(fmaxf(acc[mi][ni][r] + bv, 0.0f) * outscale);
        *(u16x4*)((unsigned short*)C_ +
                  (((size_t)(bb * 1024 + col)) << 10) + s) = pk;
      } else {
#pragma unroll
        for (int r = 0; r < 4; ++r) {
          float v = fmaxf(acc[mi][ni][r] + bv, 0.0f) * outscale;
          ((unsigned short*)C_)[(size_t)(row0 + r) * Nd + col] = f2bf(v);
        }
      }
    }
  }
}

// ---------------------------------------------------------------------------
// Kernel 2b (out_gemm): 2-barrier body, both operands bf16 gld16. (Unchanged.)
// ---------------------------------------------------------------------------
DEV void gemm_body_bf16(unsigned short* __restrict__ Asl,
                        unsigned short* __restrict__ Bsl,
                        const unsigned short* __restrict__ A,
                        const unsigned short* __restrict__ Bt,
                        const float* __restrict__ bias, float* __restrict__ C_,
                        int m0, int n0) {
  constexpr int Kd = 1024, Nd = 1024;
  const int t = threadIdx.x, lane = t & 63, wave = t >> 6;
  const int grp = lane >> 4, r16 = lane & 15;
  const int wm = wave >> 1, wn = wave & 1;
  const int swz = (r16 & 7) << 4;
  f32x4 acc[4][4] = {};
  for (int kt = 0; kt < Kd; kt += 64) {
#pragma unroll
    for (int j = 0; j < 4; ++j) {
      int chunk = (wave * 4 + j) * 64 + lane;
      int row = chunk >> 3, c = chunk & 7;
      int csw = c ^ (row & 7);
      gld16(Bt + (size_t)(n0 + row) * Kd + kt + csw * 8,
            (char*)Bsl + (wave * 4 + j) * 1024);
      gld16(A + (size_t)(m0 + row) * Kd + kt + csw * 8,
            (char*)Asl + (wave * 4 + j) * 1024);
    }
    __syncthreads();
#pragma unroll
    for (int cs = 0; cs < 2; ++cs) {
      b16x8 af[4], bfr[4];
#pragma unroll
      for (int mi = 0; mi < 4; ++mi)
        af[mi] = *(const b16x8*)((char*)Asl + (wm * 64 + mi * 16 + r16) * 128 +
                                 ((cs * 64 + grp * 16) ^ swz));
#pragma unroll
      for (int ni = 0; ni < 4; ++ni)
        bfr[ni] = *(const b16x8*)((char*)Bsl + (wn * 64 + ni * 16 + r16) * 128 +
                                  ((cs * 64 + grp * 16) ^ swz));
#pragma unroll
      for (int mi = 0; mi < 4; ++mi)
#pragma unroll
        for (int ni = 0; ni < 4; ++ni)
          acc[mi][ni] = __builtin_amdgcn_mfma_f32_16x16x32_bf16(
              af[mi], bfr[ni], acc[mi][ni], 0, 0, 0);
    }
    __syncthreads();
  }
#pragma unroll
  for (int mi = 0; mi < 4; ++mi) {
#pragma unroll
    for (int ni = 0; ni < 4; ++ni) {
      int col = n0 + wn * 64 + ni * 16 + r16;
      float bv = bias[col];
      int row0 = m0 + wm * 64 + mi * 16 + grp * 4;
#pragma unroll
      for (int r = 0; r < 4; ++r) {
        float v = fmaxf(acc[mi][ni][r] + bv, 0.0f);
        C_[(size_t)(row0 + r) * Nd + col] = v;
      }
    }
  }
}

// Q projection pre-scaled by 1/sqrt(D)*log2(e) so attention softmax runs in
// exp2 domain with no per-score scaling (relu commutes with positive scale).
static constexpr float QSCALE = 0.03125f * 1.4426950408889634f;

// x-grid 256 = 8 xcd * 32; per XCD: 8 m-panels x 4 n-tiles per z ->
// A-panel shared by 4 blocks in-XCD, weight (2MB) L2-resident.
__global__ __launch_bounds__(512) void proj3_kernel(
    const float* __restrict__ Q, const float* __restrict__ K,
    const float* __restrict__ V, const unsigned short* __restrict__ Wt,
    const float* __restrict__ bQ, const float* __restrict__ bK,
    const float* __restrict__ bV, unsigned short* __restrict__ Qp,
    unsigned short* __restrict__ Kp, unsigned short* __restrict__ VpT) {
  __shared__ unsigned short Asl[128 * 64] __attribute__((aligned(16)));
  __shared__ unsigned short Bsl[2 * 256 * 64] __attribute__((aligned(16)));
  const size_t DD = (size_t)Dsz * Dsz;
  const int bid = blockIdx.x;  // 256 = 8 xcd * 32
  const int id2 = (bid & 7) * 32 + (bid >> 3);
  const int n0 = (id2 & 3) * 256, m0 = (id2 >> 2) * 128;
  const int z = blockIdx.z;
  if (z == 0)
    gemm_body_f32<1>(Asl, Bsl, Q, Wt, bQ, Qp, m0, n0, QSCALE);
  else if (z == 1)
    gemm_body_f32<1>(Asl, Bsl, K, Wt + DD, bK, Kp, m0, n0, 1.0f);
  else
    gemm_body_f32<2>(Asl, Bsl, V, Wt + 2 * DD, bV, VpT, m0, n0, 1.0f);
}

__global__ __launch_bounds__(256) void out_gemm_kernel(
    const unsigned short* __restrict__ AO,
    const unsigned short* __restrict__ WOt, const float* __restrict__ bO,
    float* __restrict__ Out) {
  __shared__ unsigned short Asl[128 * 64] __attribute__((aligned(16)));
  __shared__ unsigned short Bsl[128 * 64] __attribute__((aligned(16)));
  const int bid = blockIdx.x;
  const int id2 = (bid & 7) * 64 + (bid >> 3);
  const int n0 = (id2 & 7) * 128, m0 = (id2 >> 3) * 128;
  gemm_body_bf16(Asl, Bsl, AO, WOt, bO, Out, m0, n0);
}

// ---------------------------------------------------------------------------
// Kernel 4: flash attention — R13's proven 2-subtile version, verbatim
// (55.3 us measured). Swapped-QK^T, NO max tracking, fexp2, l via
// ones-column, setprio, issue-early dbuf staging.
// ---------------------------------------------------------------------------
__global__ __launch_bounds__(512, 4) void attn_kernel(
    const unsigned short* __restrict__ Qp, const unsigned short* __restrict__ Kp,
    const unsigned short* __restrict__ VpT, unsigned short* __restrict__ AO) {
  __shared__ unsigned short Ks[2][64 * 64] __attribute__((aligned(16)));
  __shared__ unsigned short Vs[2][64 * 64] __attribute__((aligned(16)));
  __shared__ unsigned short Ps[16][16 * 64] __attribute__((aligned(16)));
  const int t = threadIdx.x, lane = t & 63, wave = t >> 6;
  const int grp = lane >> 4, r16 = lane & 15;
  const int bid = blockIdx.x;
  const int id2 = (bid & 7) * 64 + (bid >> 3);
  const int q0 = (id2 & 3) * 256;
  const int bh = id2 >> 2;
  const int b = bh & 7, head = bh >> 3;

  // staging: 512 threads cover K tile (512 x 16B) and V tile each 1:1
  const int srow = t >> 3, scc = t & 7;
  const int csw = scc ^ (srow & 7);
  const unsigned short* kbase = Kp + ((size_t)b * Ssz) * Dsz + head * 64;
  const unsigned short* vbase = VpT + ((size_t)b * Dsz + head * 64) * Ssz;

  // Q fragments for both subtiles (B-operand layout: row=lane&15, k=8*grp+j)
  const int sqA = q0 + wave * 16 + r16;
  const unsigned short* qbA = Qp + ((size_t)b * Ssz + sqA) * Dsz + head * 64;
  const unsigned short* qbB = qbA + (size_t)128 * Dsz;
  b16x8 qfA0 = *(const b16x8*)(qbA + grp * 8);
  b16x8 qfA1 = *(const b16x8*)(qbA + 32 + grp * 8);
  b16x8 qfB0 = *(const b16x8*)(qbB + grp * 8);
  b16x8 qfB1 = *(const b16x8*)(qbB + 32 + grp * 8);

  f32x4 oA[4] = {}, oB[4] = {};
  f32x4 olA = {}, olB = {};
  const f32x4 zero4 = {0.0f, 0.0f, 0.0f, 0.0f};
  const b16x8 ones = {16256, 16256, 16256, 16256,
                      16256, 16256, 16256, 16256};  // bf16 1.0 x8

  auto stage = [&](int kv0, int pb) {
    gld16(kbase + (size_t)(kv0 + srow) * Dsz + csw * 8,
          (char*)Ks[pb] + wave * 1024);
    gld16(vbase + (size_t)srow * Ssz + kv0 + csw * 8,
          (char*)Vs[pb] + wave * 1024);
  };

  stage(0, 0);
  __syncthreads();
  int cur = 0;

  for (int it = 0; it < 16; ++it) {
    if (it < 15) stage((it + 1) * 64, cur ^ 1);  // issue-early: overlaps compute

    // S^T = K Q^T for both subtiles, sharing the K fragment loads.
    __builtin_amdgcn_s_setprio(1);
    f32x4 scA[4], scB[4];
#pragma unroll
    for (int f = 0; f < 4; ++f) {
      int k = f * 16 + r16;
      int kswz = (k & 7) << 4;
      const char* kb = (const char*)Ks[cur] + k * 128;
      b16x8 kf0 = *(const b16x8*)(kb + ((grp * 16) ^ kswz));
      b16x8 kf1 = *(const b16x8*)(kb + ((64 + grp * 16) ^ kswz));
      f32x4 sA = __builtin_amdgcn_mfma_f32_16x16x32_bf16(kf0, qfA0, zero4, 0, 0, 0);
      scA[f] = __builtin_amdgcn_mfma_f32_16x16x32_bf16(kf1, qfA1, sA, 0, 0, 0);
      f32x4 sB = __builtin_amdgcn_mfma_f32_16x16x32_bf16(kf0, qfB0, zero4, 0, 0, 0);
      scB[f] = __builtin_amdgcn_mfma_f32_16x16x32_bf16(kf1, qfB1, sB, 0, 0, 0);
    }
    __builtin_amdgcn_s_setprio(0);

    // p = exp2(s) via raw v_exp_f32; pack P rows: 8B writes via cvt_pk
    {
      int qs = (r16 & 7) << 4;
      char* prowA = (char*)Ps + (wave * 2 + 0) * 2048 + r16 * 128;
      char* prowB = (char*)Ps + (wave * 2 + 1) * 2048 + r16 * 128;
#pragma unroll
      for (int f = 0; f < 4; ++f) {
        u32x2 w;
        w[0] = cvt2(fexp2(scA[f][0]), fexp2(scA[f][1]));
        w[1] = cvt2(fexp2(scA[f][2]), fexp2(scA[f][3]));
        *(u32x2*)(prowA + ((f * 32 + grp * 8) ^ qs)) = w;
      }
#pragma unroll
      for (int f = 0; f < 4; ++f) {
        u32x2 w;
        w[0] = cvt2(fexp2(scB[f][0]), fexp2(scB[f][1]));
        w[1] = cvt2(fexp2(scB[f][2]), fexp2(scB[f][3]));
        *(u32x2*)(prowB + ((f * 32 + grp * 8) ^ qs)) = w;
      }
    }

    // O += P V ; l += P 1 — V fragments shared across subtiles
    __builtin_amdgcn_s_setprio(1);
#pragma unroll
    for (int ks = 0; ks < 2; ++ks) {
      int pswz = (r16 & 7) << 4;
      int poff = r16 * 128 + ((ks * 64 + grp * 16) ^ pswz);
      b16x8 paA = *(const b16x8*)((char*)Ps + (wave * 2 + 0) * 2048 + poff);
      b16x8 paB = *(const b16x8*)((char*)Ps + (wave * 2 + 1) * 2048 + poff);
      olA = __builtin_amdgcn_mfma_f32_16x16x32_bf16(paA, ones, olA, 0, 0, 0);
      olB = __builtin_amdgcn_mfma_f32_16x16x32_bf16(paB, ones, olB, 0, 0, 0);
#pragma unroll
      for (int fc = 0; fc < 4; ++fc) {
        int d = fc * 16 + r16;
        int vswz = (d & 7) << 4;
        b16x8 vb = *(const b16x8*)((char*)Vs[cur] + d * 128 +
                                   ((ks * 64 + grp * 16) ^ vswz));
        oA[fc] = __builtin_amdgcn_mfma_f32_16x16x32_bf16(paA, vb, oA[fc], 0, 0, 0);
        oB[fc] = __builtin_amdgcn_mfma_f32_16x16x32_bf16(paB, vb, oB[fc], 0, 0, 0);
      }
    }
    __builtin_amdgcn_s_setprio(0);
    __syncthreads();  // drains next-tile vmcnt after compute; read-fence for swap
    cur ^= 1;
  }

  // O /= l ; o and ol share the D-layout (row q = grp*4+r) -> no broadcast
#pragma unroll
  for (int fc = 0; fc < 4; ++fc) {
    int col = head * 64 + fc * 16 + r16;
#pragma unroll
    for (int r = 0; r < 4; ++r) {
      int rowA = q0 + wave * 16 + grp * 4 + r;
      AO[((size_t)b * Ssz + rowA) * Dsz + col] = f2bf(oA[fc][r] / olA[r]);
      AO[((size_t)b * Ssz + rowA + 128) * Dsz + col] = f2bf(oB[fc][r] / olB[r]);
    }
  }
}

// ---------------------------------------------------------------------------
extern "C" void kernel_launch(void* const* d_in, const int* in_sizes, int n_in,
                              void* d_out, int out_size, void* d_ws,
                              size_t ws_size, hipStream_t stream) {
  const float* Q = (const float*)d_in[0];
  const float* K = (const float*)d_in[1];
  const float* V = (const float*)d_in[2];
  const float* WQ = (const float*)d_in[3];
  const float* bQ = (const float*)d_in[4];
  const float* WK = (const float*)d_in[5];
  const float* bK = (const float*)d_in[6];
  const float* WV = (const float*)d_in[7];
  const float* bV = (const float*)d_in[8];
  const float* WO = (const float*)d_in[9];
  const float* bO = (const float*)d_in[10];

  char* ws = (char*)d_ws;
  const size_t MB = 1024ull * 1024ull;
  const size_t DD = (size_t)Dsz * Dsz;
  unsigned short* Wt = (unsigned short*)(ws);             // 8 MB: 4x[n][k] bf16
  unsigned short* Qp = (unsigned short*)(ws + 8 * MB);    // 16 MB
  unsigned short* Kp = (unsigned short*)(ws + 24 * MB);   // 16 MB
  unsigned short* VpT = (unsigned short*)(ws + 40 * MB);  // 16 MB
  unsigned short* AO = (unsigned short*)(ws + 56 * MB);   // 16 MB

  wconv_kernel<<<dim3(16, 16, 4), 256, 0, stream>>>(WQ, WK, WV, WO, Wt);
  proj3_kernel<<<dim3(256, 1, 3), 512, 0, stream>>>(Q, K, V, Wt, bQ, bK, bV,
                                                    Qp, Kp, VpT);
  attn_kernel<<<512, 512, 0, stream>>>(Qp, Kp, VpT, AO);
  out_gemm_kernel<<<512, 256, 0, stream>>>(AO, Wt + 3 * DD, bO, (float*)d_out);
}

// Round 18
// 150.452 us; speedup vs baseline: 1.2102x; 1.0140x over previous
//
#include <hip/hip_runtime.h>
#include <hip/hip_bf16.h>
#include <cstdint>

#define DEV __device__ __forceinline__

typedef __attribute__((ext_vector_type(4))) float f32x4;
typedef __attribute__((ext_vector_type(8))) short b16x8;
typedef __attribute__((ext_vector_type(4))) unsigned short u16x4;
typedef __attribute__((ext_vector_type(8))) unsigned short u16x8;
typedef __attribute__((ext_vector_type(2))) unsigned int u32x2;
typedef __attribute__((ext_vector_type(4))) unsigned int u32x4;

typedef __attribute__((address_space(1))) void gvoid_t;
typedef __attribute__((address_space(3))) void lvoid_t;

static constexpr int Bsz = 8, Ssz = 1024, Dsz = 1024;
static constexpr int Mrows = Bsz * Ssz;  // 8192

// async global->LDS, 16B per lane; lds base must be wave-uniform (HW adds lane*16)
DEV void gld16(const void* g, void* l) {
  __builtin_amdgcn_global_load_lds((gvoid_t*)(uintptr_t)g,
                                   (lvoid_t*)(unsigned)(uintptr_t)l, 16, 0, 0);
}

// fp32 -> bf16 RNE (finite inputs only) — cold paths only
DEV unsigned short f2bf(float x) {
  unsigned int u = __float_as_uint(x);
  u += 0x7fffu + ((u >> 16) & 1u);
  return (unsigned short)(u >> 16);
}

// hot path: paired convert -> v_cvt_pk_bf16_f32
DEV unsigned int cvt2(float lo, float hi) {
  __hip_bfloat162 h = __float22bfloat162_rn(make_float2(lo, hi));
  unsigned int u;
  __builtin_memcpy(&u, &h, 4);
  return u;
}

// raw v_exp_f32 (2^x). Safe here: x in [0, ~26] (post-ReLU scores).
// [R13 confirmed: attn 65.5 -> 55.3 us vs OCML exp2f]
DEV float fexp2(float x) {
#if __has_builtin(__builtin_amdgcn_exp2f)
  return __builtin_amdgcn_exp2f(x);
#else
  return exp2f(x);
#endif
}

// ---------------------------------------------------------------------------
// Kernel 1: convert+transpose 4 weight matrices: Wt[w][n][k] = bf16(W[k][n])
// ---------------------------------------------------------------------------
__global__ __launch_bounds__(256) void wconv_kernel(
    const float* __restrict__ WQ, const float* __restrict__ WK,
    const float* __restrict__ WV, const float* __restrict__ WO,
    unsigned short* __restrict__ Wt) {
  __shared__ float tile[64][65];
  const int w = blockIdx.z;
  const float* W = (w == 0) ? WQ : (w == 1) ? WK : (w == 2) ? WV : WO;
  const int k0 = blockIdx.x * 64, n0 = blockIdx.y * 64;
  const int t = threadIdx.x;
  {
    const int r = t >> 4;
    const int c = (t & 15) * 4;
#pragma unroll
    for (int i = 0; i < 4; ++i) {
      f32x4 v = *(const f32x4*)(W + (size_t)(k0 + i * 16 + r) * Dsz + n0 + c);
      tile[i * 16 + r][c + 0] = v[0];
      tile[i * 16 + r][c + 1] = v[1];
      tile[i * 16 + r][c + 2] = v[2];
      tile[i * 16 + r][c + 3] = v[3];
    }
  }
  __syncthreads();
  {
    const int n = t >> 2;
    const int ks = (t & 3) * 16;
    unsigned short* dst =
        Wt + (size_t)w * Dsz * Dsz + (size_t)(n0 + n) * Dsz + k0 + ks;
#pragma unroll
    for (int j = 0; j < 16; j += 4) {
      u16x4 p;
#pragma unroll
      for (int jj = 0; jj < 4; ++jj) p[jj] = f2bf(tile[ks + j + jj][n]);
      *(u16x4*)(dst + j) = p;
    }
  }
}

// ---------------------------------------------------------------------------
// Kernel 2: pipelined 128(M)x256(N)-tile GEMM, 8 waves (512 thr).
//   A (fp32 or bf16): reg-prefetch 1 K-step ahead -> convert/copy -> ds_write.
//   B: LDS dbuf via gld16, issued after barrier1, in flight across barrier2.
//   barrier1 = __syncthreads (full drain); barrier2 = lgkm-only raw s_barrier
//   (guards Asl WAR only — R17 proven).
//   OUT_MODE: 0 = fp32 row-major, 1 = bf16 row-major,
//             2 = bf16 transposed VpT[b][col][s]
// ---------------------------------------------------------------------------
template <bool A_BF16, int OUT_MODE>
DEV void gemm_body(unsigned short* __restrict__ Asl,   // 16 KB
                   unsigned short* __restrict__ Bsl,   // 2 x 32 KB
                   const void* __restrict__ A_,
                   const unsigned short* __restrict__ Bt,
                   const float* __restrict__ bias, void* __restrict__ C_,
                   int m0, int n0, float outscale) {
  constexpr int Kd = 1024, Nd = 1024;
  const int t = threadIdx.x, lane = t & 63, wave = t >> 6;
  const int grp = lane >> 4, r16 = lane & 15;
  const int wm = wave >> 2, wn = wave & 3;  // 2m x 4n waves, 64x64 each
  const int swz = (r16 & 7) << 4;
  f32x4 acc[4][4] = {};
  f32x4 aregf[2][2];  // fp32 variant: 2 chunks x 8 floats = 16 VGPR
  u32x4 aregb[2];     // bf16 variant: 2 chunks x 8 bf16 = 8 VGPR

  auto loadA = [&](int kt) {
#pragma unroll
    for (int it = 0; it < 2; ++it) {
      int chunk = it * 512 + t;
      int row = chunk >> 3, c = chunk & 7;
      int csw = c ^ (row & 7);
      if constexpr (A_BF16) {
        const unsigned short* A = (const unsigned short*)A_;
        aregb[it] = *(const u32x4*)(A + (size_t)(m0 + row) * Kd + kt + csw * 8);
      } else {
        const float* A = (const float*)A_;
        const float* src = A + (size_t)(m0 + row) * Kd + kt + csw * 8;
        aregf[it][0] = *(const f32x4*)src;
        aregf[it][1] = *(const f32x4*)(src + 4);
      }
    }
  };
  auto writeA = [&]() {
#pragma unroll
    for (int it = 0; it < 2; ++it) {
      int chunk = it * 512 + t;
      if constexpr (A_BF16) {
        *(u32x4*)((char*)Asl + chunk * 16) = aregb[it];
      } else {
        u32x4 w;
        w[0] = cvt2(aregf[it][0][0], aregf[it][0][1]);
        w[1] = cvt2(aregf[it][0][2], aregf[it][0][3]);
        w[2] = cvt2(aregf[it][1][0], aregf[it][1][1]);
        w[3] = cvt2(aregf[it][1][2], aregf[it][1][3]);
        *(u32x4*)((char*)Asl + chunk * 16) = w;
      }
    }
  };
  auto stageB = [&](int kt, int pb) {
#pragma unroll
    for (int j = 0; j < 4; ++j) {
      int chunk = (wave * 4 + j) * 64 + lane;  // 0..2047 -> 256 rows
      int row = chunk >> 3, c = chunk & 7;
      int csw = c ^ (row & 7);
      gld16(Bt + (size_t)(n0 + row) * Kd + kt + csw * 8,
            (char*)Bsl + pb * 32768 + (wave * 4 + j) * 1024);
    }
  };

  loadA(0);
  stageB(0, 0);  // prologue B[0]: drained at first barrier1 (one-time cost)
  int cur = 0;
  for (int kt = 0; kt < Kd; kt += 64) {
    writeA();        // compiler waits A(kt) reg loads here
    __syncthreads(); // barrier1: full drain — Asl visible, Bsl[cur] landed
    if (kt < Kd - 64) {
      stageB(kt + 64, cur ^ 1);  // stays in flight across barrier2
      loadA(kt + 64);            // A regs for next iter
    }
#pragma unroll
    for (int cs = 0; cs < 2; ++cs) {
      b16x8 af[4], bfr[4];
#pragma unroll
      for (int mi = 0; mi < 4; ++mi)
        af[mi] = *(const b16x8*)((char*)Asl + (wm * 64 + mi * 16 + r16) * 128 +
                                 ((cs * 64 + grp * 16) ^ swz));
#pragma unroll
      for (int ni = 0; ni < 4; ++ni)
        bfr[ni] = *(const b16x8*)((char*)Bsl + cur * 32768 +
                                  (wn * 64 + ni * 16 + r16) * 128 +
                                  ((cs * 64 + grp * 16) ^ swz));
#pragma unroll
      for (int mi = 0; mi < 4; ++mi)
#pragma unroll
        for (int ni = 0; ni < 4; ++ni)
          acc[mi][ni] = __builtin_amdgcn_mfma_f32_16x16x32_bf16(
              af[mi], bfr[ni], acc[mi][ni], 0, 0, 0);
    }
    // barrier2 (lgkm-only): guards Asl WAR; does NOT drain vmcnt
    asm volatile("s_waitcnt lgkmcnt(0)" ::: "memory");
    __builtin_amdgcn_s_barrier();
    __builtin_amdgcn_sched_barrier(0);
    cur ^= 1;
  }
  // epilogue: bias + relu (+scale); C/D layout: col=lane&15, row=(lane>>4)*4+r
#pragma unroll
  for (int mi = 0; mi < 4; ++mi) {
#pragma unroll
    for (int ni = 0; ni < 4; ++ni) {
      int col = n0 + wn * 64 + ni * 16 + r16;
      float bv = bias[col];
      int row0 = m0 + wm * 64 + mi * 16 + grp * 4;
      if constexpr (OUT_MODE == 2) {
        int bb = row0 >> 10, s = row0 & 1023;
        u16x4 pk;
#pragma unroll
        for (int r = 0; r < 4; ++r)
          pk[r] = f2bf(fmaxf(acc[mi][ni][r] + bv, 0.0f) * outscale);
        *(u16x4*)((unsigned short*)C_ +
                  (((size_t)(bb * 1024 + col)) << 10) + s) = pk;
      } else {
#pragma unroll
        for (int r = 0; r < 4; ++r) {
          float v = fmaxf(acc[mi][ni][r] + bv, 0.0f) * outscale;
          if constexpr (OUT_MODE == 1)
            ((unsigned short*)C_)[(size_t)(row0 + r) * Nd + col] = f2bf(v);
          else
            ((float*)C_)[(size_t)(row0 + r) * Nd + col] = v;
        }
      }
    }
  }
}

// Q projection pre-scaled by 1/sqrt(D)*log2(e) so attention softmax runs in
// exp2 domain with no per-score scaling (relu commutes with positive scale).
static constexpr float QSCALE = 0.03125f * 1.4426950408889634f;

// x-grid 256 = 8 xcd * 32; per XCD: 8 m-panels x 4 n-tiles per z ->
// A-panel shared by 4 blocks in-XCD, weight (2MB) L2-resident.
__global__ __launch_bounds__(512) void proj3_kernel(
    const float* __restrict__ Q, const float* __restrict__ K,
    const float* __restrict__ V, const unsigned short* __restrict__ Wt,
    const float* __restrict__ bQ, const float* __restrict__ bK,
    const float* __restrict__ bV, unsigned short* __restrict__ Qp,
    unsigned short* __restrict__ Kp, unsigned short* __restrict__ VpT) {
  __shared__ unsigned short Asl[128 * 64] __attribute__((aligned(16)));
  __shared__ unsigned short Bsl[2 * 256 * 64] __attribute__((aligned(16)));
  const size_t DD = (size_t)Dsz * Dsz;
  const int bid = blockIdx.x;  // 256 = 8 xcd * 32
  const int id2 = (bid & 7) * 32 + (bid >> 3);
  const int n0 = (id2 & 3) * 256, m0 = (id2 >> 2) * 128;
  const int z = blockIdx.z;
  if (z == 0)
    gemm_body<false, 1>(Asl, Bsl, Q, Wt, bQ, Qp, m0, n0, QSCALE);
  else if (z == 1)
    gemm_body<false, 1>(Asl, Bsl, K, Wt + DD, bK, Kp, m0, n0, 1.0f);
  else
    gemm_body<false, 2>(Asl, Bsl, V, Wt + 2 * DD, bV, VpT, m0, n0, 1.0f);
}

// R18: out_gemm ported onto the same pipelined body, bf16 A reg-staged
// (half the A bytes of proj3's fp32 path, no cvt chain) — replaces the
// stage->full-drain->compute 2-barrier rhythm whose barrier1 exposed the
// full load latency.
__global__ __launch_bounds__(512) void out_gemm_kernel(
    const unsigned short* __restrict__ AO,
    const unsigned short* __restrict__ WOt, const float* __restrict__ bO,
    float* __restrict__ Out) {
  __shared__ unsigned short Asl[128 * 64] __attribute__((aligned(16)));
  __shared__ unsigned short Bsl[2 * 256 * 64] __attribute__((aligned(16)));
  const int bid = blockIdx.x;  // 256 = 8 xcd * 32
  const int id2 = (bid & 7) * 32 + (bid >> 3);
  const int n0 = (id2 & 3) * 256, m0 = (id2 >> 2) * 128;
  gemm_body<true, 0>(Asl, Bsl, AO, WOt, bO, Out, m0, n0, 1.0f);
}

// ---------------------------------------------------------------------------
// Kernel 4: flash attention — R13's proven 2-subtile version, verbatim
// (55.3 us measured). Swapped-QK^T, NO max tracking, fexp2, l via
// ones-column, setprio, issue-early dbuf staging.
// ---------------------------------------------------------------------------
__global__ __launch_bounds__(512, 4) void attn_kernel(
    const unsigned short* __restrict__ Qp, const unsigned short* __restrict__ Kp,
    const unsigned short* __restrict__ VpT, unsigned short* __restrict__ AO) {
  __shared__ unsigned short Ks[2][64 * 64] __attribute__((aligned(16)));
  __shared__ unsigned short Vs[2][64 * 64] __attribute__((aligned(16)));
  __shared__ unsigned short Ps[16][16 * 64] __attribute__((aligned(16)));
  const int t = threadIdx.x, lane = t & 63, wave = t >> 6;
  const int grp = lane >> 4, r16 = lane & 15;
  const int bid = blockIdx.x;
  const int id2 = (bid & 7) * 64 + (bid >> 3);
  const int q0 = (id2 & 3) * 256;
  const int bh = id2 >> 2;
  const int b = bh & 7, head = bh >> 3;

  // staging: 512 threads cover K tile (512 x 16B) and V tile each 1:1
  const int srow = t >> 3, scc = t & 7;
  const int csw = scc ^ (srow & 7);
  const unsigned short* kbase = Kp + ((size_t)b * Ssz) * Dsz + head * 64;
  const unsigned short* vbase = VpT + ((size_t)b * Dsz + head * 64) * Ssz;

  // Q fragments for both subtiles (B-operand layout: row=lane&15, k=8*grp+j)
  const int sqA = q0 + wave * 16 + r16;
  const unsigned short* qbA = Qp + ((size_t)b * Ssz + sqA) * Dsz + head * 64;
  const unsigned short* qbB = qbA + (size_t)128 * Dsz;
  b16x8 qfA0 = *(const b16x8*)(qbA + grp * 8);
  b16x8 qfA1 = *(const b16x8*)(qbA + 32 + grp * 8);
  b16x8 qfB0 = *(const b16x8*)(qbB + grp * 8);
  b16x8 qfB1 = *(const b16x8*)(qbB + 32 + grp * 8);

  f32x4 oA[4] = {}, oB[4] = {};
  f32x4 olA = {}, olB = {};
  const f32x4 zero4 = {0.0f, 0.0f, 0.0f, 0.0f};
  const b16x8 ones = {16256, 16256, 16256, 16256,
                      16256, 16256, 16256, 16256};  // bf16 1.0 x8

  auto stage = [&](int kv0, int pb) {
    gld16(kbase + (size_t)(kv0 + srow) * Dsz + csw * 8,
          (char*)Ks[pb] + wave * 1024);
    gld16(vbase + (size_t)srow * Ssz + kv0 + csw * 8,
          (char*)Vs[pb] + wave * 1024);
  };

  stage(0, 0);
  __syncthreads();
  int cur = 0;

  for (int it = 0; it < 16; ++it) {
    if (it < 15) stage((it + 1) * 64, cur ^ 1);  // issue-early: overlaps compute

    // S^T = K Q^T for both subtiles, sharing the K fragment loads.
    __builtin_amdgcn_s_setprio(1);
    f32x4 scA[4], scB[4];
#pragma unroll
    for (int f = 0; f < 4; ++f) {
      int k = f * 16 + r16;
      int kswz = (k & 7) << 4;
      const char* kb = (const char*)Ks[cur] + k * 128;
      b16x8 kf0 = *(const b16x8*)(kb + ((grp * 16) ^ kswz));
      b16x8 kf1 = *(const b16x8*)(kb + ((64 + grp * 16) ^ kswz));
      f32x4 sA = __builtin_amdgcn_mfma_f32_16x16x32_bf16(kf0, qfA0, zero4, 0, 0, 0);
      scA[f] = __builtin_amdgcn_mfma_f32_16x16x32_bf16(kf1, qfA1, sA, 0, 0, 0);
      f32x4 sB = __builtin_amdgcn_mfma_f32_16x16x32_bf16(kf0, qfB0, zero4, 0, 0, 0);
      scB[f] = __builtin_amdgcn_mfma_f32_16x16x32_bf16(kf1, qfB1, sB, 0, 0, 0);
    }
    __builtin_amdgcn_s_setprio(0);

    // p = exp2(s) via raw v_exp_f32; pack P rows: 8B writes via cvt_pk
    {
      int qs = (r16 & 7) << 4;
      char* prowA = (char*)Ps + (wave * 2 + 0) * 2048 + r16 * 128;
      char* prowB = (char*)Ps + (wave * 2 + 1) * 2048 + r16 * 128;
#pragma unroll
      for (int f = 0; f < 4; ++f) {
        u32x2 w;
        w[0] = cvt2(fexp2(scA[f][0]), fexp2(scA[f][1]));
        w[1] = cvt2(fexp2(scA[f][2]), fexp2(scA[f][3]));
        *(u32x2*)(prowA + ((f * 32 + grp * 8) ^ qs)) = w;
      }
#pragma unroll
      for (int f = 0; f < 4; ++f) {
        u32x2 w;
        w[0] = cvt2(fexp2(scB[f][0]), fexp2(scB[f][1]));
        w[1] = cvt2(fexp2(scB[f][2]), fexp2(scB[f][3]));
        *(u32x2*)(prowB + ((f * 32 + grp * 8) ^ qs)) = w;
      }
    }

    // O += P V ; l += P 1 — V fragments shared across subtiles
    __builtin_amdgcn_s_setprio(1);
#pragma unroll
    for (int ks = 0; ks < 2; ++ks) {
      int pswz = (r16 & 7) << 4;
      int poff = r16 * 128 + ((ks * 64 + grp * 16) ^ pswz);
      b16x8 paA = *(const b16x8*)((char*)Ps + (wave * 2 + 0) * 2048 + poff);
      b16x8 paB = *(const b16x8*)((char*)Ps + (wave * 2 + 1) * 2048 + poff);
      olA = __builtin_amdgcn_mfma_f32_16x16x32_bf16(paA, ones, olA, 0, 0, 0);
      olB = __builtin_amdgcn_mfma_f32_16x16x32_bf16(paB, ones, olB, 0, 0, 0);
#pragma unroll
      for (int fc = 0; fc < 4; ++fc) {
        int d = fc * 16 + r16;
        int vswz = (d & 7) << 4;
        b16x8 vb = *(const b16x8*)((char*)Vs[cur] + d * 128 +
                                   ((ks * 64 + grp * 16) ^ vswz));
        oA[fc] = __builtin_amdgcn_mfma_f32_16x16x32_bf16(paA, vb, oA[fc], 0, 0, 0);
        oB[fc] = __builtin_amdgcn_mfma_f32_16x16x32_bf16(paB, vb, oB[fc], 0, 0, 0);
      }
    }
    __builtin_amdgcn_s_setprio(0);
    __syncthreads();  // drains next-tile vmcnt after compute; read-fence for swap
    cur ^= 1;
  }

  // O /= l ; o and ol share the D-layout (row q = grp*4+r) -> no broadcast
#pragma unroll
  for (int fc = 0; fc < 4; ++fc) {
    int col = head * 64 + fc * 16 + r16;
#pragma unroll
    for (int r = 0; r < 4; ++r) {
      int rowA = q0 + wave * 16 + grp * 4 + r;
      AO[((size_t)b * Ssz + rowA) * Dsz + col] = f2bf(oA[fc][r] / olA[r]);
      AO[((size_t)b * Ssz + rowA + 128) * Dsz + col] = f2bf(oB[fc][r] / olB[r]);
    }
  }
}

// ---------------------------------------------------------------------------
extern "C" void kernel_launch(void* const* d_in, const int* in_sizes, int n_in,
                              void* d_out, int out_size, void* d_ws,
                              size_t ws_size, hipStream_t stream) {
  const float* Q = (const float*)d_in[0];
  const float* K = (const float*)d_in[1];
  const float* V = (const float*)d_in[2];
  const float* WQ = (const float*)d_in[3];
  const float* bQ = (const float*)d_in[4];
  const float* WK = (const float*)d_in[5];
  const float* bK = (const float*)d_in[6];
  const float* WV = (const float*)d_in[7];
  const float* bV = (const float*)d_in[8];
  const float* WO = (const float*)d_in[9];
  const float* bO = (const float*)d_in[10];

  char* ws = (char*)d_ws;
  const size_t MB = 1024ull * 1024ull;
  const size_t DD = (size_t)Dsz * Dsz;
  unsigned short* Wt = (unsigned short*)(ws);             // 8 MB: 4x[n][k] bf16
  unsigned short* Qp = (unsigned short*)(ws + 8 * MB);    // 16 MB
  unsigned short* Kp = (unsigned short*)(ws + 24 * MB);   // 16 MB
  unsigned short* VpT = (unsigned short*)(ws + 40 * MB);  // 16 MB
  unsigned short* AO = (unsigned short*)(ws + 56 * MB);   // 16 MB

  wconv_kernel<<<dim3(16, 16, 4), 256, 0, stream>>>(WQ, WK, WV, WO, Wt);
  proj3_kernel<<<dim3(256, 1, 3), 512, 0, stream>>>(Q, K, V, Wt, bQ, bK, bV,
                                                    Qp, Kp, VpT);
  attn_kernel<<<512, 512, 0, stream>>>(Qp, Kp, VpT, AO);
  out_gemm_kernel<<<256, 512, 0, stream>>>(AO, Wt + 3 * DD, bO, (float*)d_out);
}